// Round 4
// baseline (2336.547 us; speedup 1.0000x reference)
//
#include <hip/hip_runtime.h>

#define H_ 300
#define B_ 1024
#define N_ 49152
#define XSTR 328   // ushort stride for 16-row bf16 tiles
#define HSTR 304
#define WDIR 291840   // ushorts per direction = 57 jobs * 10 kt * 512
#define XGROW 912

typedef __attribute__((ext_vector_type(8))) short short8;
typedef __attribute__((ext_vector_type(4))) float f32x4;

__device__ __forceinline__ unsigned short f2bf(float f) {
  unsigned int u = __float_as_uint(f);
  u += 0x7FFFu + ((u >> 16) & 1u);
  return (unsigned short)(u >> 16);
}
__device__ __forceinline__ unsigned pack2bf(float a, float b) {
  return (unsigned)f2bf(a) | ((unsigned)f2bf(b) << 16);
}
__device__ __forceinline__ float bf2f(unsigned short u) {
  return __uint_as_float(((unsigned)u) << 16);
}

// ---------- segment start/len ----------
__global__ void seg_kernel(const int* __restrict__ batch, const int* __restrict__ pos,
                           int* __restrict__ seg_start, int* __restrict__ seg_len) {
  int i = blockIdx.x * blockDim.x + threadIdx.x;
  if (i >= N_) return;
  int b = batch[i], p = pos[i];
  if (p == 0) seg_start[b] = i;
  if (i == N_ - 1 || batch[i + 1] != b) seg_len[b] = p + 1;
}

// ---------- h0 = segment max ----------
__global__ void h0_kernel(const float* __restrict__ node, const int* __restrict__ seg_start,
                          const int* __restrict__ seg_len, float* __restrict__ h0) {
  int g = blockIdx.x;
  int col = threadIdx.x;
  if (col >= H_) return;
  int s0 = seg_start[g], L = seg_len[g];
  const float* p = node + (size_t)s0 * H_ + col;
  float ma = p[0], mb = -3.4e38f, mc = -3.4e38f, md = -3.4e38f;
  int r = 1;
  for (; r + 3 < L; r += 4) {
    ma = fmaxf(ma, p[(size_t)r * H_]);
    mb = fmaxf(mb, p[(size_t)(r + 1) * H_]);
    mc = fmaxf(mc, p[(size_t)(r + 2) * H_]);
    md = fmaxf(md, p[(size_t)(r + 3) * H_]);
  }
  for (; r < L; ++r) ma = fmaxf(ma, p[(size_t)r * H_]);
  h0[g * H_ + col] = fmaxf(fmaxf(ma, mb), fmaxf(mc, md));
}

// ---------- ih weights -> per-ct fragment layout (for xg_kernel) ----------
// dst[dir][((ct*3+g)*10+kt)*512 + lane*8 + i]
__global__ void wpack_ih(const float* __restrict__ wf, const float* __restrict__ wbk,
                         unsigned short* __restrict__ wib) {
  int f = blockIdx.x * 256 + threadIdx.x;
  if (f >= WDIR) return;
  int dir = blockIdx.y;
  const float* src = dir ? wbk : wf;
  int i = f & 7, lane = (f >> 3) & 63, r = f >> 9;
  int kt = r % 10; r /= 10;
  int g = r % 3;  r /= 3;
  int ct = r;
  int k = kt * 32 + ((lane >> 4) << 3) + i;
  int col = ct * 16 + (lane & 15);
  float v = 0.f;
  if (col < 300 && k < 300) v = src[(g * 300 + col) * 300 + k];
  wib[(size_t)dir * WDIR + f] = f2bf(v);
}

// ---------- hh weights -> per-wave contiguous job-stream layout (for gru3) ----------
// wave w jobs: tiles {w, 8+w (,16+w if w<3)} x gates (r,z,n); jobbase(w)=w<3? w*9 : 27+(w-3)*6
// dst[dir][ (jobbase+j)*10*512 + kt*512 + lane*8 + i ]
__global__ void wpack_hh(const float* __restrict__ wf, const float* __restrict__ wbk,
                         unsigned short* __restrict__ whb2) {
  int f = blockIdx.x * 256 + threadIdx.x;
  if (f >= WDIR) return;
  int dir = blockIdx.y;
  const float* src = dir ? wbk : wf;
  int i = f & 7, lane = (f >> 3) & 63, r = f >> 9;
  int kt = r % 10; r /= 10;
  int jg = r;  // 0..56
  int w, j;
  if (jg < 27) { w = jg / 9; j = jg % 9; }
  else         { w = 3 + (jg - 27) / 6; j = (jg - 27) % 6; }
  int ti = j / 3, gate = j % 3;
  int ct = (ti == 2) ? 16 + w : ti * 8 + w;
  int k = kt * 32 + ((lane >> 4) << 3) + i;
  int col = ct * 16 + (lane & 15);
  float v = 0.f;
  if (col < 300 && k < 300) v = src[(gate * 300 + col) * 300 + k];
  whb2[(size_t)dir * WDIR + f] = f2bf(v);
}

// ---------- xg = relu(node+bias) @ W_ih^T ----------
__global__ __launch_bounds__(256) void xg_kernel(const float* __restrict__ node,
                                                 const float* __restrict__ biasv,
                                                 const unsigned short* __restrict__ wib,
                                                 unsigned short* __restrict__ xg) {
  __shared__ unsigned short AS[64 * XSTR];
  int tid = threadIdx.x, mb = blockIdx.x, dir = blockIdx.y;
  int row0 = mb * 64;
  for (int idx = tid; idx < 64 * 82; idx += 256) {
    int rr = idx / 82, c4 = idx - rr * 82;
    uint2 pk = {0u, 0u};
    if (c4 < 75) {
      float4 v = *(const float4*)(node + (size_t)(row0 + rr) * 300 + c4 * 4);
      float4 bv = *(const float4*)(biasv + c4 * 4);
      pk.x = pack2bf(fmaxf(v.x + bv.x, 0.f), fmaxf(v.y + bv.y, 0.f));
      pk.y = pack2bf(fmaxf(v.z + bv.z, 0.f), fmaxf(v.w + bv.w, 0.f));
    }
    *(uint2*)&AS[rr * XSTR + c4 * 4] = pk;
  }
  __syncthreads();
  int lane = tid & 63, wave = tid >> 6;
  const unsigned short* wb = wib + (size_t)dir * WDIR;
  int arow = (lane & 15) * XSTR + ((lane >> 4) << 3);
  for (int ct = wave; ct < 19; ct += 4) {
    f32x4 acc[3][4] = {};
    const unsigned short* wt = wb + ct * (3 * 10 * 512) + lane * 8;
    #pragma unroll
    for (int kt = 0; kt < 10; ++kt) {
      short8 b0 = *(const short8*)(wt + kt * 512);
      short8 b1 = *(const short8*)(wt + (10 + kt) * 512);
      short8 b2 = *(const short8*)(wt + (20 + kt) * 512);
      #pragma unroll
      for (int m = 0; m < 4; ++m) {
        short8 a = *(const short8*)&AS[m * 16 * XSTR + arow + kt * 32];
        acc[0][m] = __builtin_amdgcn_mfma_f32_16x16x32_bf16(a, b0, acc[0][m], 0, 0, 0);
        acc[1][m] = __builtin_amdgcn_mfma_f32_16x16x32_bf16(a, b1, acc[1][m], 0, 0, 0);
        acc[2][m] = __builtin_amdgcn_mfma_f32_16x16x32_bf16(a, b2, acc[2][m], 0, 0, 0);
      }
    }
    int col = ct * 16 + (lane & 15);
    if (col < 300) {
      int rl0 = (lane >> 4) * 4;
      #pragma unroll
      for (int g = 0; g < 3; ++g)
        #pragma unroll
        for (int m = 0; m < 4; ++m)
          #pragma unroll
          for (int i = 0; i < 4; ++i) {
            int row = row0 + m * 16 + rl0 + i;
            xg[((size_t)dir * N_ + row) * XGROW + g * 304 + col] = f2bf(acc[g][m][i]);
          }
    }
  }
}

// ---------- recurrence: triple-buffered contiguous weight stream ----------
// 128 blocks x 512 thr (8 waves), 16 seqs/block. Wave w: tiles {w, 8+w (,16+w)}.
// Job = (tile,gate) = 10 frags. Buffers B0(r)/B1(z)/B2(n); prefetch 2 jobs ahead,
// wrapping across the step barrier (weight addresses are t-invariant).
__global__ __launch_bounds__(512) __attribute__((amdgpu_waves_per_eu(2, 2)))
void gru3_kernel(const unsigned short* __restrict__ whb2,
                 const unsigned short* __restrict__ xg,
                 const float* __restrict__ h0,
                 const float* __restrict__ b_ih_f, const float* __restrict__ b_hh_f,
                 const float* __restrict__ b_ih_b, const float* __restrict__ b_hh_b,
                 const int* __restrict__ seg_start, const int* __restrict__ seg_len,
                 float* __restrict__ out) {
  __shared__ unsigned short HBF[2][16 * XSTR];
  __shared__ float HS[16 * HSTR];
  __shared__ float BCr[304], BCz[304], BCni[304], BCnh[304];
  __shared__ int SST[16], SLN[16];

  int tid = threadIdx.x, blk = blockIdx.x;
  int dir = blk >> 6, db = blk & 63;

  if (tid < 16) {
    int g = (db < 32) ? 2 * (db * 16 + tid) : 2 * ((db - 32) * 16 + tid) + 1;
    SST[tid] = seg_start[g];
    SLN[tid] = seg_len[g];
  }
  const float* bi = dir ? b_ih_b : b_ih_f;
  const float* bh = dir ? b_hh_b : b_hh_f;
  for (int i2 = tid; i2 < 304; i2 += 512) {
    bool v = i2 < 300;
    BCr[i2] = v ? bi[i2] + bh[i2] : 0.f;
    BCz[i2] = v ? bi[300 + i2] + bh[300 + i2] : 0.f;
    BCni[i2] = v ? bi[600 + i2] : 0.f;
    BCnh[i2] = v ? bh[600 + i2] : 0.f;
  }
  for (int idx = tid; idx < 16 * 82; idx += 512) {
    int s = idx / 82, c4 = idx - s * 82;
    int g = (db < 32) ? 2 * (db * 16 + s) : 2 * ((db - 32) * 16 + s) + 1;
    float4 v = {0.f, 0.f, 0.f, 0.f};
    if (c4 < 75) v = *(const float4*)(h0 + (size_t)g * 300 + c4 * 4);
    if (c4 < 76) *(float4*)&HS[s * HSTR + c4 * 4] = v;
    uint2 pk;
    pk.x = pack2bf(v.x, v.y);
    pk.y = pack2bf(v.z, v.w);
    *(uint2*)&HBF[0][s * XSTR + c4 * 4] = pk;
    uint2 z = {0u, 0u};
    *(uint2*)&HBF[1][s * XSTR + c4 * 4] = z;
  }
  __syncthreads();

  int nsteps = 64;
  if (dir == 0) {
    int m = 0;
    for (int s = 0; s < 16; ++s) m = max(m, SLN[s]);
    nsteps = m;
  }

  int lane = tid & 63, wave = tid >> 6;
  int NT = (wave < 3) ? 3 : 2;
  int jobbase = (wave < 3) ? wave * 9 : 27 + (wave - 3) * 6;
  const unsigned short* sbase = whb2 + (size_t)dir * WDIR + (size_t)jobbase * 5120 + lane * 8;
  int arow = (lane & 15) * XSTR + ((lane >> 4) << 3);
  int lcol = lane & 15, s0w = (lane >> 4) * 4;
  int col0 = wave * 16 + lcol, col1 = (8 + wave) * 16 + lcol, col2 = (16 + wave) * 16 + lcol;

  float bir0 = BCr[col0], biz0 = BCz[col0], bni0 = BCni[col0], bnh0 = BCnh[col0];
  float bir1 = BCr[col1], biz1 = BCz[col1], bni1 = BCni[col1], bnh1 = BCnh[col1];
  float bir2 = 0.f, biz2 = 0.f, bni2 = 0.f, bnh2 = 0.f;
  if (NT == 3) { bir2 = BCr[col2]; biz2 = BCz[col2]; bni2 = BCni[col2]; bnh2 = BCnh[col2]; }

  int stl[4], lnl[4];
  #pragma unroll
  for (int i = 0; i < 4; ++i) { stl[i] = SST[s0w + i]; lnl[i] = SLN[s0w + i]; }
  const unsigned short* xgd = xg + (size_t)dir * N_ * XGROW;

  short8 B0[10], B1[10], B2[10], AH[10];
  int tt_cur = 0, wb_cur = 0;

  auto tile_body = [&](int col, int jn, int jr2, int jz2,
                       float bir, float biz, float bni, float bnh) {
    float xr[4], xz[4], xn[4];
    #pragma unroll
    for (int i = 0; i < 4; ++i) {
      bool v = (col < 300) && (tt_cur < lnl[i]);
      const unsigned short* xp = xgd + (size_t)(stl[i] + tt_cur) * XGROW + col;
      xr[i] = v ? bf2f(xp[0]) : 0.f;
      xz[i] = v ? bf2f(xp[304]) : 0.f;
      xn[i] = v ? bf2f(xp[608]) : 0.f;
    }
    f32x4 ar = {0, 0, 0, 0}, az = {0, 0, 0, 0}, an = {0, 0, 0, 0};
    // prefetch n of this tile -> B2; consume B0 (r)
    #pragma unroll
    for (int kt = 0; kt < 10; ++kt) B2[kt] = *(const short8*)(sbase + (size_t)(jn * 10 + kt) * 512);
    #pragma unroll
    for (int kt = 0; kt < 10; ++kt)
      ar = __builtin_amdgcn_mfma_f32_16x16x32_bf16(AH[kt], B0[kt], ar, 0, 0, 0);
    // prefetch next r -> B0; consume B1 (z)
    #pragma unroll
    for (int kt = 0; kt < 10; ++kt) B0[kt] = *(const short8*)(sbase + (size_t)(jr2 * 10 + kt) * 512);
    #pragma unroll
    for (int kt = 0; kt < 10; ++kt)
      az = __builtin_amdgcn_mfma_f32_16x16x32_bf16(AH[kt], B1[kt], az, 0, 0, 0);
    // prefetch next z -> B1; consume B2 (n)
    #pragma unroll
    for (int kt = 0; kt < 10; ++kt) B1[kt] = *(const short8*)(sbase + (size_t)(jz2 * 10 + kt) * 512);
    #pragma unroll
    for (int kt = 0; kt < 10; ++kt)
      an = __builtin_amdgcn_mfma_f32_16x16x32_bf16(AH[kt], B2[kt], an, 0, 0, 0);
    // gates + h update
    #pragma unroll
    for (int i = 0; i < 4; ++i) {
      int s = s0w + i;
      float pr = ar[i] + xr[i] + bir;
      float pz = az[i] + xz[i] + biz;
      float rr = 1.f / (1.f + __expf(-pr));
      float zz = 1.f / (1.f + __expf(-pz));
      float pn = (xn[i] + bni) + rr * (an[i] + bnh);
      float nn = 1.f - 2.f / (__expf(2.f * pn) + 1.f);
      float ho = HS[s * HSTR + col];
      float hn = fmaf(zz, ho - nn, nn);
      HS[s * HSTR + col] = hn;
      HBF[wb_cur][s * XSTR + col] = f2bf(hn);
      if (col < 300 && tt_cur < lnl[i])
        out[(size_t)(stl[i] + tt_cur) * 600 + dir * 300 + col] = hn;
    }
  };

  // prologue: job0 -> B0, job1 -> B1
  #pragma unroll
  for (int kt = 0; kt < 10; ++kt) B0[kt] = *(const short8*)(sbase + (size_t)kt * 512);
  #pragma unroll
  for (int kt = 0; kt < 10; ++kt) B1[kt] = *(const short8*)(sbase + (size_t)(10 + kt) * 512);

  for (int t = 0; t < nsteps; ++t) {
    tt_cur = dir ? 63 - t : t;
    int rb = t & 1;
    wb_cur = rb ^ 1;
    const unsigned short* hb = &HBF[rb][0];
    #pragma unroll
    for (int kt = 0; kt < 10; ++kt) AH[kt] = *(const short8*)&hb[arow + kt * 32];

    tile_body(col0, 2, 3, 4, bir0, biz0, bni0, bnh0);
    if (NT == 3) {
      tile_body(col1, 5, 6, 7, bir1, biz1, bni1, bnh1);
      tile_body(col2, 8, 0, 1, bir2, biz2, bni2, bnh2);
    } else {
      tile_body(col1, 5, 0, 1, bir1, biz1, bni1, bnh1);
    }
    __syncthreads();
  }
}

extern "C" void kernel_launch(void* const* d_in, const int* in_sizes, int n_in,
                              void* d_out, int out_size, void* d_ws, size_t ws_size,
                              hipStream_t stream) {
  const float* node   = (const float*)d_in[0];
  const int*   batch  = (const int*)d_in[1];
  const int*   pos    = (const int*)d_in[2];
  const float* bias   = (const float*)d_in[3];
  const float* w_ih_f = (const float*)d_in[4];
  const float* w_hh_f = (const float*)d_in[5];
  const float* b_ih_f = (const float*)d_in[6];
  const float* b_hh_f = (const float*)d_in[7];
  const float* w_ih_b = (const float*)d_in[8];
  const float* w_hh_b = (const float*)d_in[9];
  const float* b_ih_b = (const float*)d_in[10];
  const float* b_hh_b = (const float*)d_in[11];
  float* outp = (float*)d_out;

  // ws layout: whb2 | wib | h0 | seg_start | seg_len | xg
  size_t off_whb = 0;
  size_t off_wib = off_whb + (size_t)2 * WDIR * 2;   // 1,167,360
  size_t off_h0  = off_wib + (size_t)2 * WDIR * 2;   // 2,334,720
  size_t off_ss  = off_h0 + (size_t)B_ * H_ * 4;     // 3,563,520
  size_t off_sl  = off_ss + 4096;
  size_t off_xg  = off_sl + 4096;

  unsigned short* whb2 = (unsigned short*)((char*)d_ws + off_whb);
  unsigned short* wib  = (unsigned short*)((char*)d_ws + off_wib);
  float* h0 = (float*)((char*)d_ws + off_h0);
  int* seg_start = (int*)((char*)d_ws + off_ss);
  int* seg_len = (int*)((char*)d_ws + off_sl);
  unsigned short* xg = (unsigned short*)((char*)d_ws + off_xg);

  seg_kernel<<<(N_ + 255) / 256, 256, 0, stream>>>(batch, pos, seg_start, seg_len);
  h0_kernel<<<B_, 320, 0, stream>>>(node, seg_start, seg_len, h0);
  wpack_ih<<<dim3(WDIR / 256, 2), 256, 0, stream>>>(w_ih_f, w_ih_b, wib);
  wpack_hh<<<dim3(WDIR / 256, 2), 256, 0, stream>>>(w_hh_f, w_hh_b, whb2);
  xg_kernel<<<dim3(N_ / 64, 2), 256, 0, stream>>>(node, bias, wib, xg);
  gru3_kernel<<<128, 512, 0, stream>>>(whb2, xg, h0, b_ih_f, b_hh_f, b_ih_b, b_hh_b,
                                       seg_start, seg_len, outp);
}